// Round 2
// baseline (1261.848 us; speedup 1.0000x reference)
//
#include <hip/hip_runtime.h>
#include <stdint.h>

#define T_TOK 4096
#define HID   2048
#define INTER 2816
#define NEXP  8
#define ACT_ROWS 8320   // 8192 assignments + 128 pad rows for tail tiles

typedef __attribute__((ext_vector_type(8))) short short8;
typedef __attribute__((ext_vector_type(4))) float f32x4;

// ---------- helpers ----------
__device__ __forceinline__ unsigned short f2bf(float f) {
    union { float f; unsigned u; } x; x.f = f;
    unsigned u = x.u + 0x7fffu + ((x.u >> 16) & 1u);   // RNE
    return (unsigned short)(u >> 16);
}

__device__ __forceinline__ void async16(const void* g, void* l) {
    __builtin_amdgcn_global_load_lds(
        (const __attribute__((address_space(1))) unsigned int*)g,
        (__attribute__((address_space(3))) unsigned int*)l, 16, 0, 0);
}

// ---------- ws layout (bytes) ----------
#define OFF_HBF 0ull
#define OFF_ACT (16ull*1024*1024)                       // 16,777,216
#define OFF_CNT (OFF_ACT + (unsigned long long)ACT_ROWS*INTER*2)  // 63,635,456
#define OFF_CUR (OFF_CNT + 32)
#define OFF_OFS (OFF_CNT + 64)
#define OFF_TKE (OFF_CNT + 128)
#define OFF_TKW (OFF_TKE + 32768)
#define OFF_LT  (OFF_TKW + 32768)
#define OFF_LW  (OFF_LT  + 32768)

// ---------- small kernels ----------
__global__ void k_convert(const float* __restrict__ src, short* __restrict__ dst, int n8) {
    int i = blockIdx.x * 256 + threadIdx.x;
    if (i >= n8) return;
    const f32x4* p = (const f32x4*)src + (size_t)i * 2;
    f32x4 a = p[0], b = p[1];
    short8 v;
    v[0] = f2bf(a[0]); v[1] = f2bf(a[1]); v[2] = f2bf(a[2]); v[3] = f2bf(a[3]);
    v[4] = f2bf(b[0]); v[5] = f2bf(b[1]); v[6] = f2bf(b[2]); v[7] = f2bf(b[3]);
    ((short8*)dst)[i] = v;
}

__global__ void k_route(const float* __restrict__ logits, int* __restrict__ counts,
                        int* __restrict__ topk_e, float* __restrict__ topk_w) {
    int t = blockIdx.x * 256 + threadIdx.x;
    if (t >= T_TOK) return;
    const f32x4* p = (const f32x4*)(logits + (size_t)t * NEXP);
    f32x4 a = p[0], b = p[1];
    float l[8] = {a[0], a[1], a[2], a[3], b[0], b[1], b[2], b[3]};
    float m = l[0];
    #pragma unroll
    for (int i = 1; i < 8; i++) m = fmaxf(m, l[i]);
    float e[8];
    #pragma unroll
    for (int i = 0; i < 8; i++) e[i] = expf(l[i] - m);
    int i0 = 0; float b0 = e[0]; int i1 = -1; float b1 = -1.f;
    #pragma unroll
    for (int i = 1; i < 8; i++) {
        if (e[i] > b0)      { b1 = b0; i1 = i0; b0 = e[i]; i0 = i; }
        else if (e[i] > b1) { b1 = e[i]; i1 = i; }
    }
    float inv = 1.f / (b0 + b1);
    topk_e[2*t]   = i0; topk_w[2*t]   = b0 * inv;
    topk_e[2*t+1] = i1; topk_w[2*t+1] = b1 * inv;
    atomicAdd(&counts[i0], 1);
    atomicAdd(&counts[i1], 1);
}

__global__ void k_scan(const int* __restrict__ counts, int* __restrict__ offsets) {
    if (threadIdx.x == 0) {
        int r = 0;
        for (int e2 = 0; e2 < NEXP; e2++) { offsets[e2] = r; r += counts[e2]; }
    }
}

__global__ void k_scatter(const int* __restrict__ topk_e, const float* __restrict__ topk_w,
                          const int* __restrict__ offsets, int* __restrict__ cursors,
                          int* __restrict__ list_tok, float* __restrict__ list_w) {
    int t = blockIdx.x * 256 + threadIdx.x;
    if (t >= T_TOK) return;
    #pragma unroll
    for (int k = 0; k < 2; k++) {
        int e = topk_e[2*t + k];
        int pos = offsets[e] + atomicAdd(&cursors[e], 1);
        list_tok[pos] = t;
        list_w[pos] = topk_w[2*t + k];
    }
}

// ---------- GEMM1: act = silu(h @ w13_gate^T) * (h @ w13_up^T), gathered rows ----------
// grid: (INTER/64=44, 32, 8). block 256 = 4 waves (2x2), tile 128 tokens x 64 act cols.
__global__ __launch_bounds__(256)
void k_gemm1(const float* __restrict__ w13, const short* __restrict__ hbf,
             short* __restrict__ act, const int* __restrict__ counts,
             const int* __restrict__ offsets, const int* __restrict__ list_tok) {
    const int e = blockIdx.z;
    const int cnt = counts[e];
    const int moff = blockIdx.y * 128;
    if (moff >= cnt) return;
    const int base = offsets[e];
    const int j0 = blockIdx.x * 64;

    __shared__ short As[128 * 64];
    __shared__ short Bs[128 * 64];
    char* asl = (char*)As;
    char* bsl = (char*)Bs;

    const int tid = threadIdx.x;
    const int lane = tid & 63, w = tid >> 6;
    const int hi = lane >> 4, lo = lane & 15;
    const int wr = w >> 1, wc = w & 1;

    // A staging precompute: 1024 16B-chunks; chunk c -> row=c>>3, slot=c&7 (swizzled source)
    const char* hbytes = (const char*)hbf;
    const char* agsrc[4];
    #pragma unroll
    for (int i = 0; i < 4; i++) {
        int c = (i * 4 + w) * 64 + lane;
        int row = c >> 3, slot = c & 7;
        int tr = moff + row;
        int tok = (tr < cnt) ? list_tok[base + tr] : list_tok[base];
        int ss = slot ^ (row & 7);
        agsrc[i] = hbytes + (size_t)tok * HID * 2 + ss * 16;
    }
    // B staging precompute: rows 0..63 = gate j0+r, rows 64..127 = up INTER+j0+(r-64)
    const float* bsrc[4];
    int bbyte[4];
    #pragma unroll
    for (int i = 0; i < 4; i++) {
        int s = i * 256 + tid;
        int brow = s >> 3, slot = s & 7;
        int srcrow = (brow < 64) ? (j0 + brow) : (INTER + j0 + (brow - 64));
        bsrc[i] = w13 + ((size_t)e * (2 * INTER) + srcrow) * HID + slot * 8;
        bbyte[i] = brow * 128 + ((slot ^ (brow & 7)) * 16);
    }

    f32x4 acc[4][4];
    #pragma unroll
    for (int m = 0; m < 4; m++)
        #pragma unroll
        for (int n = 0; n < 4; n++) acc[m][n] = (f32x4){0.f, 0.f, 0.f, 0.f};

    for (int k0 = 0; k0 < HID; k0 += 64) {
        __syncthreads();
        #pragma unroll
        for (int i = 0; i < 4; i++)
            async16(agsrc[i] + k0 * 2, asl + ((i * 4 + w) * 64) * 16);
        #pragma unroll
        for (int i = 0; i < 4; i++) {
            const f32x4* p = (const f32x4*)(bsrc[i] + k0);
            f32x4 x = p[0], y = p[1];
            short8 v;
            v[0] = f2bf(x[0]); v[1] = f2bf(x[1]); v[2] = f2bf(x[2]); v[3] = f2bf(x[3]);
            v[4] = f2bf(y[0]); v[5] = f2bf(y[1]); v[6] = f2bf(y[2]); v[7] = f2bf(y[3]);
            *(short8*)(bsl + bbyte[i]) = v;
        }
        __syncthreads();
        #pragma unroll
        for (int kk = 0; kk < 2; kk++) {
            short8 af[4], bq[4];
            #pragma unroll
            for (int m = 0; m < 4; m++) {
                int row = wr * 64 + m * 16 + lo;
                int slot = (kk * 4 + hi) ^ (row & 7);
                af[m] = *(const short8*)(asl + row * 128 + slot * 16);
            }
            #pragma unroll
            for (int n = 0; n < 4; n++) {
                int row = ((n < 2) ? 0 : 64) + wc * 32 + (n & 1) * 16 + lo;
                int slot = (kk * 4 + hi) ^ (row & 7);
                bq[n] = *(const short8*)(bsl + row * 128 + slot * 16);
            }
            #pragma unroll
            for (int m = 0; m < 4; m++)
                #pragma unroll
                for (int n = 0; n < 4; n++)
                    acc[m][n] = __builtin_amdgcn_mfma_f32_16x16x32_bf16(af[m], bq[n], acc[m][n], 0, 0, 0);
        }
    }

    // epilogue: act = silu(gate)*up, bf16
    #pragma unroll
    for (int m = 0; m < 4; m++) {
        int rbase = wr * 64 + m * 16 + hi * 4;
        #pragma unroll
        for (int r = 0; r < 4; r++) {
            int tr = moff + rbase + r;
            if (tr >= cnt) continue;
            size_t arow = (size_t)(base + tr) * INTER;
            #pragma unroll
            for (int n2 = 0; n2 < 2; n2++) {
                float g = acc[m][n2][r];
                float u = acc[m][n2 + 2][r];
                float s = g / (1.f + expf(-g));
                act[arow + j0 + wc * 32 + n2 * 16 + lo] = (short)f2bf(s * u);
            }
        }
    }
}

// ---------- GEMM2: out[tok] += w * (act @ w2^T) ----------
// grid: (HID/128=16, 32, 8). block 256 = 4 waves (2x2), tile 128 slots x 128 out cols.
__global__ __launch_bounds__(256)
void k_gemm2(const float* __restrict__ w2, const short* __restrict__ act,
             float* __restrict__ out, const int* __restrict__ counts,
             const int* __restrict__ offsets, const int* __restrict__ list_tok,
             const float* __restrict__ list_w) {
    const int e = blockIdx.z;
    const int cnt = counts[e];
    const int moff = blockIdx.y * 128;
    if (moff >= cnt) return;
    const int base = offsets[e];
    const int n0 = blockIdx.x * 128;

    __shared__ short As[128 * 64];
    __shared__ short Bs[128 * 64];
    char* asl = (char*)As;
    char* bsl = (char*)Bs;

    const int tid = threadIdx.x;
    const int lane = tid & 63, w = tid >> 6;
    const int hi = lane >> 4, lo = lane & 15;
    const int wr = w >> 1, wc = w & 1;

    const char* abytes = (const char*)act;
    const char* agsrc[4];
    #pragma unroll
    for (int i = 0; i < 4; i++) {
        int c = (i * 4 + w) * 64 + lane;
        int row = c >> 3, slot = c & 7;
        int ss = slot ^ (row & 7);
        agsrc[i] = abytes + (size_t)(base + moff + row) * INTER * 2 + ss * 16;  // padded to ACT_ROWS
    }
    const float* bsrc[4];
    int bbyte[4];
    #pragma unroll
    for (int i = 0; i < 4; i++) {
        int s = i * 256 + tid;
        int brow = s >> 3, slot = s & 7;
        bsrc[i] = w2 + ((size_t)e * HID + (n0 + brow)) * INTER + slot * 8;
        bbyte[i] = brow * 128 + ((slot ^ (brow & 7)) * 16);
    }

    f32x4 acc[4][4];
    #pragma unroll
    for (int m = 0; m < 4; m++)
        #pragma unroll
        for (int n = 0; n < 4; n++) acc[m][n] = (f32x4){0.f, 0.f, 0.f, 0.f};

    for (int k0 = 0; k0 < INTER; k0 += 64) {
        __syncthreads();
        #pragma unroll
        for (int i = 0; i < 4; i++)
            async16(agsrc[i] + k0 * 2, asl + ((i * 4 + w) * 64) * 16);
        #pragma unroll
        for (int i = 0; i < 4; i++) {
            const f32x4* p = (const f32x4*)(bsrc[i] + k0);
            f32x4 x = p[0], y = p[1];
            short8 v;
            v[0] = f2bf(x[0]); v[1] = f2bf(x[1]); v[2] = f2bf(x[2]); v[3] = f2bf(x[3]);
            v[4] = f2bf(y[0]); v[5] = f2bf(y[1]); v[6] = f2bf(y[2]); v[7] = f2bf(y[3]);
            *(short8*)(bsl + bbyte[i]) = v;
        }
        __syncthreads();
        #pragma unroll
        for (int kk = 0; kk < 2; kk++) {
            short8 af[4], bq[4];
            #pragma unroll
            for (int m = 0; m < 4; m++) {
                int row = wr * 64 + m * 16 + lo;
                int slot = (kk * 4 + hi) ^ (row & 7);
                af[m] = *(const short8*)(asl + row * 128 + slot * 16);
            }
            #pragma unroll
            for (int n = 0; n < 4; n++) {
                int row = wc * 64 + n * 16 + lo;
                int slot = (kk * 4 + hi) ^ (row & 7);
                bq[n] = *(const short8*)(bsl + row * 128 + slot * 16);
            }
            #pragma unroll
            for (int m = 0; m < 4; m++)
                #pragma unroll
                for (int n = 0; n < 4; n++)
                    acc[m][n] = __builtin_amdgcn_mfma_f32_16x16x32_bf16(af[m], bq[n], acc[m][n], 0, 0, 0);
        }
    }

    // stage token ids + weights for this row-tile into LDS (reuse As/Bs)
    __syncthreads();
    int* tb = (int*)As;
    float* wb = (float*)Bs;
    if (tid < 128) {
        int tr = moff + tid;
        bool v = tr < cnt;
        tb[tid] = v ? list_tok[base + tr] : -1;
        wb[tid] = v ? list_w[base + tr] : 0.f;
    }
    __syncthreads();

    #pragma unroll
    for (int m = 0; m < 4; m++) {
        int rbase = wr * 64 + m * 16 + hi * 4;
        #pragma unroll
        for (int r = 0; r < 4; r++) {
            int lrow = rbase + r;
            int tok = tb[lrow];
            if (tok < 0) continue;
            float ww = wb[lrow];
            float* orow = out + (size_t)tok * HID + n0 + wc * 64 + lo;
            #pragma unroll
            for (int n = 0; n < 4; n++)
                atomicAdd(orow + n * 16, ww * acc[m][n][r]);
        }
    }
}

// ---------- launch ----------
extern "C" void kernel_launch(void* const* d_in, const int* in_sizes, int n_in,
                              void* d_out, int out_size, void* d_ws, size_t ws_size,
                              hipStream_t stream) {
    const float* hs  = (const float*)d_in[0];
    const float* rl  = (const float*)d_in[1];
    const float* w13 = (const float*)d_in[2];
    const float* w2  = (const float*)d_in[3];
    float* out = (float*)d_out;
    char* ws = (char*)d_ws;

    short* hbf     = (short*)(ws + OFF_HBF);
    short* act     = (short*)(ws + OFF_ACT);
    int*   counts  = (int*)(ws + OFF_CNT);
    int*   cursors = (int*)(ws + OFF_CUR);
    int*   offsets = (int*)(ws + OFF_OFS);
    int*   topk_e  = (int*)(ws + OFF_TKE);
    float* topk_w  = (float*)(ws + OFF_TKW);
    int*   list_tok= (int*)(ws + OFF_LT);
    float* list_w  = (float*)(ws + OFF_LW);

    hipMemsetAsync(counts, 0, 64, stream);  // counts + cursors
    hipMemsetAsync(out, 0, (size_t)T_TOK * HID * sizeof(float), stream);

    k_route<<<T_TOK / 256, 256, 0, stream>>>(rl, counts, topk_e, topk_w);
    k_scan<<<1, 64, 0, stream>>>(counts, offsets);
    k_scatter<<<T_TOK / 256, 256, 0, stream>>>(topk_e, topk_w, offsets, cursors, list_tok, list_w);
    k_convert<<<(T_TOK * HID / 8) / 256, 256, 0, stream>>>(hs, hbf, T_TOK * HID / 8);

    k_gemm1<<<dim3(INTER / 64, 32, NEXP), 256, 0, stream>>>(w13, hbf, act, counts, offsets, list_tok);
    k_gemm2<<<dim3(HID / 128, 32, NEXP), 256, 0, stream>>>(w2, act, out, counts, offsets, list_tok, list_w);
}

// Round 4
// 1240.872 us; speedup vs baseline: 1.0169x; 1.0169x over previous
//
#include <hip/hip_runtime.h>
#include <stdint.h>

#define T_TOK 4096
#define HID   2048
#define INTER 2816
#define NEXP  8
#define ACT_ROWS 8320   // 8192 assignments + 128 pad rows for tail tiles

typedef __attribute__((ext_vector_type(8))) short short8;
typedef __attribute__((ext_vector_type(4))) float f32x4;

// ---------- helpers ----------
__device__ __forceinline__ unsigned short f2bf(float f) {
    union { float f; unsigned u; } x; x.f = f;
    unsigned u = x.u + 0x7fffu + ((x.u >> 16) & 1u);   // RNE
    return (unsigned short)(u >> 16);
}

__device__ __forceinline__ void async16(const void* g, void* l) {
    __builtin_amdgcn_global_load_lds(
        (const __attribute__((address_space(1))) unsigned int*)g,
        (__attribute__((address_space(3))) unsigned int*)l, 16, 0, 0);
}

// ---------- ws layout (bytes) ----------
#define OFF_HBF 0ull
#define OFF_ACT (16ull*1024*1024)                       // 16,777,216
#define OFF_CNT (OFF_ACT + (unsigned long long)ACT_ROWS*INTER*2)  // 63,635,456
#define OFF_CUR (OFF_CNT + 32)
#define OFF_OFS (OFF_CNT + 64)
#define OFF_TKE (OFF_CNT + 128)
#define OFF_TKW (OFF_TKE + 32768)
#define OFF_LT  (OFF_TKW + 32768)
#define OFF_LW  (OFF_LT  + 32768)
// Path A extras (bf16 weights)
#define OFF_W13B 67108864ull                            // 64 MiB boundary
#define OFF_W2B  (OFF_W13B + 184549376ull)              // 251,658,240
#define NEED_A   (OFF_W2B + 92274688ull)                // 343,932,928

// ---------- small kernels ----------
__global__ void k_convert(const float* __restrict__ src, short* __restrict__ dst, int n8) {
    int i = blockIdx.x * 256 + threadIdx.x;
    if (i >= n8) return;
    const f32x4* p = (const f32x4*)src + (size_t)i * 2;
    f32x4 a = p[0], b = p[1];
    short8 v;
    v[0] = f2bf(a[0]); v[1] = f2bf(a[1]); v[2] = f2bf(a[2]); v[3] = f2bf(a[3]);
    v[4] = f2bf(b[0]); v[5] = f2bf(b[1]); v[6] = f2bf(b[2]); v[7] = f2bf(b[3]);
    ((short8*)dst)[i] = v;
}

__global__ void k_route(const float* __restrict__ logits, int* __restrict__ counts,
                        int* __restrict__ topk_e, float* __restrict__ topk_w) {
    int t = blockIdx.x * 256 + threadIdx.x;
    if (t >= T_TOK) return;
    const f32x4* p = (const f32x4*)(logits + (size_t)t * NEXP);
    f32x4 a = p[0], b = p[1];
    float l[8] = {a[0], a[1], a[2], a[3], b[0], b[1], b[2], b[3]};
    float m = l[0];
    #pragma unroll
    for (int i = 1; i < 8; i++) m = fmaxf(m, l[i]);
    float e[8];
    #pragma unroll
    for (int i = 0; i < 8; i++) e[i] = expf(l[i] - m);
    int i0 = 0; float b0 = e[0]; int i1 = -1; float b1 = -1.f;
    #pragma unroll
    for (int i = 1; i < 8; i++) {
        if (e[i] > b0)      { b1 = b0; i1 = i0; b0 = e[i]; i0 = i; }
        else if (e[i] > b1) { b1 = e[i]; i1 = i; }
    }
    float inv = 1.f / (b0 + b1);
    topk_e[2*t]   = i0; topk_w[2*t]   = b0 * inv;
    topk_e[2*t+1] = i1; topk_w[2*t+1] = b1 * inv;
    atomicAdd(&counts[i0], 1);
    atomicAdd(&counts[i1], 1);
}

__global__ void k_scan(const int* __restrict__ counts, int* __restrict__ offsets) {
    if (threadIdx.x == 0) {
        int r = 0;
        for (int e2 = 0; e2 < NEXP; e2++) { offsets[e2] = r; r += counts[e2]; }
    }
}

__global__ void k_scatter(const int* __restrict__ topk_e, const float* __restrict__ topk_w,
                          const int* __restrict__ offsets, int* __restrict__ cursors,
                          int* __restrict__ list_tok, float* __restrict__ list_w) {
    int t = blockIdx.x * 256 + threadIdx.x;
    if (t >= T_TOK) return;
    #pragma unroll
    for (int k = 0; k < 2; k++) {
        int e = topk_e[2*t + k];
        int pos = offsets[e] + atomicAdd(&cursors[e], 1);
        list_tok[pos] = t;
        list_w[pos] = topk_w[2*t + k];
    }
}

// ============================================================================
// PATH A: bf16 pre-converted weights, both A and B staged via global_load_lds
// ============================================================================

// GEMM1: act = silu(h @ w13_gate^T) * (h @ w13_up^T). grid (44, 32, 8), 256 thr.
__global__ __launch_bounds__(256)
void k_gemm1_bf(const short* __restrict__ w13b, const short* __restrict__ hbf,
                short* __restrict__ act, const int* __restrict__ counts,
                const int* __restrict__ offsets, const int* __restrict__ list_tok) {
    const int e = blockIdx.z;
    const int cnt = counts[e];
    const int moff = blockIdx.y * 128;
    if (moff >= cnt) return;
    const int base = offsets[e];
    const int j0 = blockIdx.x * 64;

    __shared__ short As[128 * 64];
    __shared__ short Bs[128 * 64];
    char* asl = (char*)As;
    char* bsl = (char*)Bs;

    const int tid = threadIdx.x;
    const int lane = tid & 63, w = tid >> 6;
    const int hi = lane >> 4, lo = lane & 15;
    const int wr = w >> 1, wc = w & 1;

    // chunk c -> row=c>>3, slot=c&7; pre-swizzled global source (ss), linear LDS dest
    const char* ag[4];
    const char* bg[4];
    #pragma unroll
    for (int i = 0; i < 4; i++) {
        int c = (i * 4 + w) * 64 + lane;
        int row = c >> 3, slot = c & 7;
        int ss = slot ^ (row & 7);
        int tr = moff + row;
        int tok = (tr < cnt) ? list_tok[base + tr] : list_tok[base];
        ag[i] = (const char*)hbf + (size_t)tok * HID * 2 + ss * 16;
        int srcrow = (row < 64) ? (j0 + row) : (INTER + j0 + (row - 64));
        bg[i] = (const char*)w13b + ((size_t)e * (2 * INTER) + srcrow) * HID * 2 + ss * 16;
    }

    f32x4 acc[4][4];
    #pragma unroll
    for (int m = 0; m < 4; m++)
        #pragma unroll
        for (int n = 0; n < 4; n++) acc[m][n] = (f32x4){0.f, 0.f, 0.f, 0.f};

    for (int k0 = 0; k0 < HID; k0 += 64) {
        __syncthreads();
        #pragma unroll
        for (int i = 0; i < 4; i++)
            async16(ag[i] + k0 * 2, asl + ((i * 4 + w) * 64) * 16);
        #pragma unroll
        for (int i = 0; i < 4; i++)
            async16(bg[i] + k0 * 2, bsl + ((i * 4 + w) * 64) * 16);
        __syncthreads();
        #pragma unroll
        for (int kk = 0; kk < 2; kk++) {
            short8 af[4], bq[4];
            #pragma unroll
            for (int m = 0; m < 4; m++) {
                int row = wr * 64 + m * 16 + lo;
                int slot = (kk * 4 + hi) ^ (row & 7);
                af[m] = *(const short8*)(asl + row * 128 + slot * 16);
            }
            #pragma unroll
            for (int n = 0; n < 4; n++) {
                int row = ((n < 2) ? 0 : 64) + wc * 32 + (n & 1) * 16 + lo;
                int slot = (kk * 4 + hi) ^ (row & 7);
                bq[n] = *(const short8*)(bsl + row * 128 + slot * 16);
            }
            #pragma unroll
            for (int m = 0; m < 4; m++)
                #pragma unroll
                for (int n = 0; n < 4; n++)
                    acc[m][n] = __builtin_amdgcn_mfma_f32_16x16x32_bf16(af[m], bq[n], acc[m][n], 0, 0, 0);
        }
    }

    #pragma unroll
    for (int m = 0; m < 4; m++) {
        int rbase = wr * 64 + m * 16 + hi * 4;
        #pragma unroll
        for (int r = 0; r < 4; r++) {
            int tr = moff + rbase + r;
            if (tr >= cnt) continue;
            size_t arow = (size_t)(base + tr) * INTER;
            #pragma unroll
            for (int n2 = 0; n2 < 2; n2++) {
                float g = acc[m][n2][r];
                float u = acc[m][n2 + 2][r];
                float s = g / (1.f + expf(-g));
                act[arow + j0 + wc * 32 + n2 * 16 + lo] = (short)f2bf(s * u);
            }
        }
    }
}

// GEMM2: out[tok] += w * (act @ w2^T). grid (16, 32, 8), 256 thr.
__global__ __launch_bounds__(256)
void k_gemm2_bf(const short* __restrict__ w2b, const short* __restrict__ act,
                float* __restrict__ out, const int* __restrict__ counts,
                const int* __restrict__ offsets, const int* __restrict__ list_tok,
                const float* __restrict__ list_w) {
    const int e = blockIdx.z;
    const int cnt = counts[e];
    const int moff = blockIdx.y * 128;
    if (moff >= cnt) return;
    const int base = offsets[e];
    const int n0 = blockIdx.x * 128;

    __shared__ short As[128 * 64];
    __shared__ short Bs[128 * 64];
    char* asl = (char*)As;
    char* bsl = (char*)Bs;

    const int tid = threadIdx.x;
    const int lane = tid & 63, w = tid >> 6;
    const int hi = lane >> 4, lo = lane & 15;
    const int wr = w >> 1, wc = w & 1;

    const char* ag[4];
    const char* bg[4];
    #pragma unroll
    for (int i = 0; i < 4; i++) {
        int c = (i * 4 + w) * 64 + lane;
        int row = c >> 3, slot = c & 7;
        int ss = slot ^ (row & 7);
        ag[i] = (const char*)act + (size_t)(base + moff + row) * INTER * 2 + ss * 16;
        bg[i] = (const char*)w2b + ((size_t)e * HID + (n0 + row)) * INTER * 2 + ss * 16;
    }

    f32x4 acc[4][4];
    #pragma unroll
    for (int m = 0; m < 4; m++)
        #pragma unroll
        for (int n = 0; n < 4; n++) acc[m][n] = (f32x4){0.f, 0.f, 0.f, 0.f};

    for (int k0 = 0; k0 < INTER; k0 += 64) {
        __syncthreads();
        #pragma unroll
        for (int i = 0; i < 4; i++)
            async16(ag[i] + k0 * 2, asl + ((i * 4 + w) * 64) * 16);
        #pragma unroll
        for (int i = 0; i < 4; i++)
            async16(bg[i] + k0 * 2, bsl + ((i * 4 + w) * 64) * 16);
        __syncthreads();
        #pragma unroll
        for (int kk = 0; kk < 2; kk++) {
            short8 af[4], bq[4];
            #pragma unroll
            for (int m = 0; m < 4; m++) {
                int row = wr * 64 + m * 16 + lo;
                int slot = (kk * 4 + hi) ^ (row & 7);
                af[m] = *(const short8*)(asl + row * 128 + slot * 16);
            }
            #pragma unroll
            for (int n = 0; n < 4; n++) {
                int row = wc * 64 + n * 16 + lo;
                int slot = (kk * 4 + hi) ^ (row & 7);
                bq[n] = *(const short8*)(bsl + row * 128 + slot * 16);
            }
            #pragma unroll
            for (int m = 0; m < 4; m++)
                #pragma unroll
                for (int n = 0; n < 4; n++)
                    acc[m][n] = __builtin_amdgcn_mfma_f32_16x16x32_bf16(af[m], bq[n], acc[m][n], 0, 0, 0);
        }
    }

    __syncthreads();
    int* tb = (int*)As;
    float* wb = (float*)Bs;
    if (tid < 128) {
        int tr = moff + tid;
        bool v = tr < cnt;
        tb[tid] = v ? list_tok[base + tr] : -1;
        wb[tid] = v ? list_w[base + tr] : 0.f;
    }
    __syncthreads();

    #pragma unroll
    for (int m = 0; m < 4; m++) {
        int rbase = wr * 64 + m * 16 + hi * 4;
        #pragma unroll
        for (int r = 0; r < 4; r++) {
            int lrow = rbase + r;
            int tok = tb[lrow];
            if (tok < 0) continue;
            float ww = wb[lrow];
            float* orow = out + (size_t)tok * HID + n0 + wc * 64 + lo;
            #pragma unroll
            for (int n = 0; n < 4; n++)
                atomicAdd(orow + n * 16, ww * acc[m][n][r]);
        }
    }
}

// ============================================================================
// PATH B (fallback, ws too small): f32 weights converted during staging
// ============================================================================

__global__ __launch_bounds__(256)
void k_gemm1(const float* __restrict__ w13, const short* __restrict__ hbf,
             short* __restrict__ act, const int* __restrict__ counts,
             const int* __restrict__ offsets, const int* __restrict__ list_tok) {
    const int e = blockIdx.z;
    const int cnt = counts[e];
    const int moff = blockIdx.y * 128;
    if (moff >= cnt) return;
    const int base = offsets[e];
    const int j0 = blockIdx.x * 64;

    __shared__ short As[128 * 64];
    __shared__ short Bs[128 * 64];
    char* asl = (char*)As;
    char* bsl = (char*)Bs;

    const int tid = threadIdx.x;
    const int lane = tid & 63, w = tid >> 6;
    const int hi = lane >> 4, lo = lane & 15;
    const int wr = w >> 1, wc = w & 1;

    const char* hbytes = (const char*)hbf;
    const char* agsrc[4];
    #pragma unroll
    for (int i = 0; i < 4; i++) {
        int c = (i * 4 + w) * 64 + lane;
        int row = c >> 3, slot = c & 7;
        int tr = moff + row;
        int tok = (tr < cnt) ? list_tok[base + tr] : list_tok[base];
        int ss = slot ^ (row & 7);
        agsrc[i] = hbytes + (size_t)tok * HID * 2 + ss * 16;
    }
    const float* bsrc[4];
    int bbyte[4];
    #pragma unroll
    for (int i = 0; i < 4; i++) {
        int s = i * 256 + tid;
        int brow = s >> 3, slot = s & 7;
        int srcrow = (brow < 64) ? (j0 + brow) : (INTER + j0 + (brow - 64));
        bsrc[i] = w13 + ((size_t)e * (2 * INTER) + srcrow) * HID + slot * 8;
        bbyte[i] = brow * 128 + ((slot ^ (brow & 7)) * 16);
    }

    f32x4 acc[4][4];
    #pragma unroll
    for (int m = 0; m < 4; m++)
        #pragma unroll
        for (int n = 0; n < 4; n++) acc[m][n] = (f32x4){0.f, 0.f, 0.f, 0.f};

    for (int k0 = 0; k0 < HID; k0 += 64) {
        __syncthreads();
        #pragma unroll
        for (int i = 0; i < 4; i++)
            async16(agsrc[i] + k0 * 2, asl + ((i * 4 + w) * 64) * 16);
        #pragma unroll
        for (int i = 0; i < 4; i++) {
            const f32x4* p = (const f32x4*)(bsrc[i] + k0);
            f32x4 x = p[0], y = p[1];
            short8 v;
            v[0] = f2bf(x[0]); v[1] = f2bf(x[1]); v[2] = f2bf(x[2]); v[3] = f2bf(x[3]);
            v[4] = f2bf(y[0]); v[5] = f2bf(y[1]); v[6] = f2bf(y[2]); v[7] = f2bf(y[3]);
            *(short8*)(bsl + bbyte[i]) = v;
        }
        __syncthreads();
        #pragma unroll
        for (int kk = 0; kk < 2; kk++) {
            short8 af[4], bq[4];
            #pragma unroll
            for (int m = 0; m < 4; m++) {
                int row = wr * 64 + m * 16 + lo;
                int slot = (kk * 4 + hi) ^ (row & 7);
                af[m] = *(const short8*)(asl + row * 128 + slot * 16);
            }
            #pragma unroll
            for (int n = 0; n < 4; n++) {
                int row = ((n < 2) ? 0 : 64) + wc * 32 + (n & 1) * 16 + lo;
                int slot = (kk * 4 + hi) ^ (row & 7);
                bq[n] = *(const short8*)(bsl + row * 128 + slot * 16);
            }
            #pragma unroll
            for (int m = 0; m < 4; m++)
                #pragma unroll
                for (int n = 0; n < 4; n++)
                    acc[m][n] = __builtin_amdgcn_mfma_f32_16x16x32_bf16(af[m], bq[n], acc[m][n], 0, 0, 0);
        }
    }

    #pragma unroll
    for (int m = 0; m < 4; m++) {
        int rbase = wr * 64 + m * 16 + hi * 4;
        #pragma unroll
        for (int r = 0; r < 4; r++) {
            int tr = moff + rbase + r;
            if (tr >= cnt) continue;
            size_t arow = (size_t)(base + tr) * INTER;
            #pragma unroll
            for (int n2 = 0; n2 < 2; n2++) {
                float g = acc[m][n2][r];
                float u = acc[m][n2 + 2][r];
                float s = g / (1.f + expf(-g));
                act[arow + j0 + wc * 32 + n2 * 16 + lo] = (short)f2bf(s * u);
            }
        }
    }
}

__global__ __launch_bounds__(256)
void k_gemm2(const float* __restrict__ w2, const short* __restrict__ act,
             float* __restrict__ out, const int* __restrict__ counts,
             const int* __restrict__ offsets, const int* __restrict__ list_tok,
             const float* __restrict__ list_w) {
    const int e = blockIdx.z;
    const int cnt = counts[e];
    const int moff = blockIdx.y * 128;
    if (moff >= cnt) return;
    const int base = offsets[e];
    const int n0 = blockIdx.x * 128;

    __shared__ short As[128 * 64];
    __shared__ short Bs[128 * 64];
    char* asl = (char*)As;
    char* bsl = (char*)Bs;

    const int tid = threadIdx.x;
    const int lane = tid & 63, w = tid >> 6;
    const int hi = lane >> 4, lo = lane & 15;
    const int wr = w >> 1, wc = w & 1;

    const char* abytes = (const char*)act;
    const char* agsrc[4];
    #pragma unroll
    for (int i = 0; i < 4; i++) {
        int c = (i * 4 + w) * 64 + lane;
        int row = c >> 3, slot = c & 7;
        int ss = slot ^ (row & 7);
        agsrc[i] = abytes + (size_t)(base + moff + row) * INTER * 2 + ss * 16;
    }
    const float* bsrc[4];
    int bbyte[4];
    #pragma unroll
    for (int i = 0; i < 4; i++) {
        int s = i * 256 + tid;
        int brow = s >> 3, slot = s & 7;
        bsrc[i] = w2 + ((size_t)e * HID + (n0 + brow)) * INTER + slot * 8;
        bbyte[i] = brow * 128 + ((slot ^ (brow & 7)) * 16);
    }

    f32x4 acc[4][4];
    #pragma unroll
    for (int m = 0; m < 4; m++)
        #pragma unroll
        for (int n = 0; n < 4; n++) acc[m][n] = (f32x4){0.f, 0.f, 0.f, 0.f};

    for (int k0 = 0; k0 < INTER; k0 += 64) {
        __syncthreads();
        #pragma unroll
        for (int i = 0; i < 4; i++)
            async16(agsrc[i] + k0 * 2, asl + ((i * 4 + w) * 64) * 16);
        #pragma unroll
        for (int i = 0; i < 4; i++) {
            const f32x4* p = (const f32x4*)(bsrc[i] + k0);
            f32x4 x = p[0], y = p[1];
            short8 v;
            v[0] = f2bf(x[0]); v[1] = f2bf(x[1]); v[2] = f2bf(x[2]); v[3] = f2bf(x[3]);
            v[4] = f2bf(y[0]); v[5] = f2bf(y[1]); v[6] = f2bf(y[2]); v[7] = f2bf(y[3]);
            *(short8*)(bsl + bbyte[i]) = v;
        }
        __syncthreads();
        #pragma unroll
        for (int kk = 0; kk < 2; kk++) {
            short8 af[4], bq[4];
            #pragma unroll
            for (int m = 0; m < 4; m++) {
                int row = wr * 64 + m * 16 + lo;
                int slot = (kk * 4 + hi) ^ (row & 7);
                af[m] = *(const short8*)(asl + row * 128 + slot * 16);
            }
            #pragma unroll
            for (int n = 0; n < 4; n++) {
                int row = wc * 64 + n * 16 + lo;
                int slot = (kk * 4 + hi) ^ (row & 7);
                bq[n] = *(const short8*)(bsl + row * 128 + slot * 16);
            }
            #pragma unroll
            for (int m = 0; m < 4; m++)
                #pragma unroll
                for (int n = 0; n < 4; n++)
                    acc[m][n] = __builtin_amdgcn_mfma_f32_16x16x32_bf16(af[m], bq[n], acc[m][n], 0, 0, 0);
        }
    }

    __syncthreads();
    int* tb = (int*)As;
    float* wb = (float*)Bs;
    if (tid < 128) {
        int tr = moff + tid;
        bool v = tr < cnt;
        tb[tid] = v ? list_tok[base + tr] : -1;
        wb[tid] = v ? list_w[base + tr] : 0.f;
    }
    __syncthreads();

    #pragma unroll
    for (int m = 0; m < 4; m++) {
        int rbase = wr * 64 + m * 16 + hi * 4;
        #pragma unroll
        for (int r = 0; r < 4; r++) {
            int lrow = rbase + r;
            int tok = tb[lrow];
            if (tok < 0) continue;
            float ww = wb[lrow];
            float* orow = out + (size_t)tok * HID + n0 + wc * 64 + lo;
            #pragma unroll
            for (int n = 0; n < 4; n++)
                atomicAdd(orow + n * 16, ww * acc[m][n][r]);
        }
    }
}

// ---------- launch ----------
extern "C" void kernel_launch(void* const* d_in, const int* in_sizes, int n_in,
                              void* d_out, int out_size, void* d_ws, size_t ws_size,
                              hipStream_t stream) {
    const float* hs  = (const float*)d_in[0];
    const float* rl  = (const float*)d_in[1];
    const float* w13 = (const float*)d_in[2];
    const float* w2  = (const float*)d_in[3];
    float* out = (float*)d_out;
    char* ws = (char*)d_ws;

    short* hbf     = (short*)(ws + OFF_HBF);
    short* act     = (short*)(ws + OFF_ACT);
    int*   counts  = (int*)(ws + OFF_CNT);
    int*   cursors = (int*)(ws + OFF_CUR);
    int*   offsets = (int*)(ws + OFF_OFS);
    int*   topk_e  = (int*)(ws + OFF_TKE);
    float* topk_w  = (float*)(ws + OFF_TKW);
    int*   list_tok= (int*)(ws + OFF_LT);
    float* list_w  = (float*)(ws + OFF_LW);

    hipMemsetAsync(counts, 0, 64, stream);  // counts + cursors
    hipMemsetAsync(out, 0, (size_t)T_TOK * HID * sizeof(float), stream);

    k_route<<<T_TOK / 256, 256, 0, stream>>>(rl, counts, topk_e, topk_w);
    k_scan<<<1, 64, 0, stream>>>(counts, offsets);
    k_scatter<<<T_TOK / 256, 256, 0, stream>>>(topk_e, topk_w, offsets, cursors, list_tok, list_w);
    k_convert<<<(T_TOK * HID / 8) / 256, 256, 0, stream>>>(hs, hbf, T_TOK * HID / 8);

    if (ws_size >= NEED_A) {
        short* w13b = (short*)(ws + OFF_W13B);
        short* w2b  = (short*)(ws + OFF_W2B);
        const int n8_w13 = NEXP * 2 * INTER * HID / 8;   // 11,534,336
        const int n8_w2  = NEXP * HID * INTER / 8;       //  5,767,168
        k_convert<<<(n8_w13 + 255) / 256, 256, 0, stream>>>(w13, w13b, n8_w13);
        k_convert<<<(n8_w2 + 255) / 256, 256, 0, stream>>>(w2, w2b, n8_w2);
        k_gemm1_bf<<<dim3(INTER / 64, 32, NEXP), 256, 0, stream>>>(w13b, hbf, act, counts, offsets, list_tok);
        k_gemm2_bf<<<dim3(HID / 128, 32, NEXP), 256, 0, stream>>>(w2b, act, out, counts, offsets, list_tok, list_w);
    } else {
        k_gemm1<<<dim3(INTER / 64, 32, NEXP), 256, 0, stream>>>(w13, hbf, act, counts, offsets, list_tok);
        k_gemm2<<<dim3(HID / 128, 32, NEXP), 256, 0, stream>>>(w2, act, out, counts, offsets, list_tok, list_w);
    }
}

// Round 5
// 1150.198 us; speedup vs baseline: 1.0971x; 1.0788x over previous
//
#include <hip/hip_runtime.h>
#include <stdint.h>

#define T_TOK 4096
#define HID   2048
#define INTER 2816
#define NEXP  8
#define ACT_ROWS 8320   // 8192 assignments + 128 pad rows for tail tiles

typedef __attribute__((ext_vector_type(8))) short short8;
typedef __attribute__((ext_vector_type(4))) float f32x4;

// ---------- helpers ----------
__device__ __forceinline__ unsigned short f2bf(float f) {
    union { float f; unsigned u; } x; x.f = f;
    unsigned u = x.u + 0x7fffu + ((x.u >> 16) & 1u);   // RNE
    return (unsigned short)(u >> 16);
}

__device__ __forceinline__ void async16(const void* g, void* l) {
    __builtin_amdgcn_global_load_lds(
        (const __attribute__((address_space(1))) unsigned int*)g,
        (__attribute__((address_space(3))) unsigned int*)l, 16, 0, 0);
}

// ---------- ws layout (bytes) ----------
#define OFF_HBF 0ull
#define OFF_ACT (16ull*1024*1024)
#define OFF_CNT (OFF_ACT + (unsigned long long)ACT_ROWS*INTER*2)
#define OFF_CUR (OFF_CNT + 32)
#define OFF_OFS (OFF_CNT + 64)
#define OFF_TKE (OFF_CNT + 128)
#define OFF_TKW (OFF_TKE + 32768)
#define OFF_LT  (OFF_TKW + 32768)
#define OFF_LW  (OFF_LT  + 32768)
#define OFF_W13B 67108864ull
#define OFF_W2B  (OFF_W13B + 184549376ull)
#define NEED_A   (OFF_W2B + 92274688ull)   // ~328 MiB — verified available in R4

// ---------- small kernels ----------
__global__ void k_convert(const float* __restrict__ src, short* __restrict__ dst, int n8) {
    int i = blockIdx.x * 256 + threadIdx.x;
    if (i >= n8) return;
    const f32x4* p = (const f32x4*)src + (size_t)i * 2;
    f32x4 a = p[0], b = p[1];
    short8 v;
    v[0] = f2bf(a[0]); v[1] = f2bf(a[1]); v[2] = f2bf(a[2]); v[3] = f2bf(a[3]);
    v[4] = f2bf(b[0]); v[5] = f2bf(b[1]); v[6] = f2bf(b[2]); v[7] = f2bf(b[3]);
    ((short8*)dst)[i] = v;
}

__global__ void k_route(const float* __restrict__ logits, int* __restrict__ counts,
                        int* __restrict__ topk_e, float* __restrict__ topk_w) {
    int t = blockIdx.x * 256 + threadIdx.x;
    if (t >= T_TOK) return;
    const f32x4* p = (const f32x4*)(logits + (size_t)t * NEXP);
    f32x4 a = p[0], b = p[1];
    float l[8] = {a[0], a[1], a[2], a[3], b[0], b[1], b[2], b[3]};
    float m = l[0];
    #pragma unroll
    for (int i = 1; i < 8; i++) m = fmaxf(m, l[i]);
    float e[8];
    #pragma unroll
    for (int i = 0; i < 8; i++) e[i] = expf(l[i] - m);
    int i0 = 0; float b0 = e[0]; int i1 = -1; float b1 = -1.f;
    #pragma unroll
    for (int i = 1; i < 8; i++) {
        if (e[i] > b0)      { b1 = b0; i1 = i0; b0 = e[i]; i0 = i; }
        else if (e[i] > b1) { b1 = e[i]; i1 = i; }
    }
    float inv = 1.f / (b0 + b1);
    topk_e[2*t]   = i0; topk_w[2*t]   = b0 * inv;
    topk_e[2*t+1] = i1; topk_w[2*t+1] = b1 * inv;
    atomicAdd(&counts[i0], 1);
    atomicAdd(&counts[i1], 1);
}

__global__ void k_scan(const int* __restrict__ counts, int* __restrict__ offsets) {
    if (threadIdx.x == 0) {
        int r = 0;
        for (int e2 = 0; e2 < NEXP; e2++) { offsets[e2] = r; r += counts[e2]; }
    }
}

__global__ void k_scatter(const int* __restrict__ topk_e, const float* __restrict__ topk_w,
                          const int* __restrict__ offsets, int* __restrict__ cursors,
                          int* __restrict__ list_tok, float* __restrict__ list_w) {
    int t = blockIdx.x * 256 + threadIdx.x;
    if (t >= T_TOK) return;
    #pragma unroll
    for (int k = 0; k < 2; k++) {
        int e = topk_e[2*t + k];
        int pos = offsets[e] + atomicAdd(&cursors[e], 1);
        list_tok[pos] = t;
        list_w[pos] = topk_w[2*t + k];
    }
}

// ============================================================================
// GEMM1: act = silu(h @ gate^T) * (h @ up^T). Tile 128 tok x 128 act cols
// (256 B-rows: gate j0..j0+127 then up j0..j0+127). 512 thr = 8 waves (2x4).
// Wave (wr,wc): rows wr*64+.., owns gate cols [wc*32,+32) and matching up cols.
// grid (INTER/128=22, 32, 8).
// ============================================================================
__global__ __launch_bounds__(512)
void k_gemm1_bf(const short* __restrict__ w13b, const short* __restrict__ hbf,
                short* __restrict__ act, const int* __restrict__ counts,
                const int* __restrict__ offsets, const int* __restrict__ list_tok) {
    const int e = blockIdx.z;
    const int cnt = counts[e];
    const int moff = blockIdx.y * 128;
    if (moff >= cnt) return;
    const int base = offsets[e];
    const int j0 = blockIdx.x * 128;

    __shared__ short As[128 * 64];   // 16 KB
    __shared__ short Bs[256 * 64];   // 32 KB
    char* asl = (char*)As;
    char* bsl = (char*)Bs;

    const int tid = threadIdx.x;
    const int lane = tid & 63, w = tid >> 6;
    const int hi = lane >> 4, lo = lane & 15;
    const int wr = w >> 2, wc = w & 3;

    // A: 1024 16B chunks (chunk c: row=c>>3, slot=c&7), pre-swizzled source
    const char* ag[2];
    #pragma unroll
    for (int i = 0; i < 2; i++) {
        int c = i * 512 + tid;
        int row = c >> 3, slot = c & 7;
        int ss = slot ^ (row & 7);
        int tr = moff + row;
        int tok = (tr < cnt) ? list_tok[base + tr] : list_tok[base];
        ag[i] = (const char*)hbf + (size_t)tok * (HID * 2) + ss * 16;
    }
    // B: 2048 chunks; rows 0..127 gate, 128..255 up
    const char* bg[4];
    #pragma unroll
    for (int i = 0; i < 4; i++) {
        int c = i * 512 + tid;
        int row = c >> 3, slot = c & 7;
        int ss = slot ^ (row & 7);
        int srcrow = (row < 128) ? (j0 + row) : (INTER + j0 + (row - 128));
        bg[i] = (const char*)w13b + ((size_t)e * (2 * INTER) + srcrow) * (HID * 2) + ss * 16;
    }

    f32x4 acc[4][4];
    #pragma unroll
    for (int m = 0; m < 4; m++)
        #pragma unroll
        for (int n = 0; n < 4; n++) acc[m][n] = (f32x4){0.f, 0.f, 0.f, 0.f};

    for (int k0 = 0; k0 < HID; k0 += 64) {
        __syncthreads();
        #pragma unroll
        for (int i = 0; i < 2; i++)
            async16(ag[i] + k0 * 2, asl + (i * 512 + w * 64) * 16);
        #pragma unroll
        for (int i = 0; i < 4; i++)
            async16(bg[i] + k0 * 2, bsl + (i * 512 + w * 64) * 16);
        __syncthreads();
        #pragma unroll
        for (int kk = 0; kk < 2; kk++) {
            short8 af[4], bq[4];
            #pragma unroll
            for (int m = 0; m < 4; m++) {
                int row = wr * 64 + m * 16 + lo;
                int slot = (kk * 4 + hi) ^ (row & 7);
                af[m] = *(const short8*)(asl + row * 128 + slot * 16);
            }
            #pragma unroll
            for (int n = 0; n < 4; n++) {
                int brow = (n < 2) ? (wc * 32 + n * 16 + lo)
                                   : (128 + wc * 32 + (n - 2) * 16 + lo);
                int slot = (kk * 4 + hi) ^ (brow & 7);
                bq[n] = *(const short8*)(bsl + brow * 128 + slot * 16);
            }
            #pragma unroll
            for (int m = 0; m < 4; m++)
                #pragma unroll
                for (int n = 0; n < 4; n++)
                    acc[m][n] = __builtin_amdgcn_mfma_f32_16x16x32_bf16(af[m], bq[n], acc[m][n], 0, 0, 0);
        }
    }

    #pragma unroll
    for (int m = 0; m < 4; m++) {
        int rbase = wr * 64 + m * 16 + hi * 4;
        #pragma unroll
        for (int r = 0; r < 4; r++) {
            int tr = moff + rbase + r;
            if (tr >= cnt) continue;
            size_t arow = (size_t)(base + tr) * INTER;
            #pragma unroll
            for (int n2 = 0; n2 < 2; n2++) {
                float g = acc[m][n2][r];
                float u = acc[m][n2 + 2][r];
                float s = g / (1.f + expf(-g));
                act[arow + j0 + wc * 32 + n2 * 16 + lo] = (short)f2bf(s * u);
            }
        }
    }
}

// ============================================================================
// GEMM2: out[tok] += w * (act @ w2^T). Tile 128 slots x 256 out cols.
// 512 thr = 8 waves (2x4). grid (HID/256=8, 32, 8).
// ============================================================================
__global__ __launch_bounds__(512)
void k_gemm2_bf(const short* __restrict__ w2b, const short* __restrict__ act,
                float* __restrict__ out, const int* __restrict__ counts,
                const int* __restrict__ offsets, const int* __restrict__ list_tok,
                const float* __restrict__ list_w) {
    const int e = blockIdx.z;
    const int cnt = counts[e];
    const int moff = blockIdx.y * 128;
    if (moff >= cnt) return;
    const int base = offsets[e];
    const int n0 = blockIdx.x * 256;

    __shared__ short As[128 * 64];   // 16 KB
    __shared__ short Bs[256 * 64];   // 32 KB
    char* asl = (char*)As;
    char* bsl = (char*)Bs;

    const int tid = threadIdx.x;
    const int lane = tid & 63, w = tid >> 6;
    const int hi = lane >> 4, lo = lane & 15;
    const int wr = w >> 2, wc = w & 3;

    const char* ag[2];
    #pragma unroll
    for (int i = 0; i < 2; i++) {
        int c = i * 512 + tid;
        int row = c >> 3, slot = c & 7;
        int ss = slot ^ (row & 7);
        ag[i] = (const char*)act + (size_t)(base + moff + row) * (INTER * 2) + ss * 16;
    }
    const char* bg[4];
    #pragma unroll
    for (int i = 0; i < 4; i++) {
        int c = i * 512 + tid;
        int row = c >> 3, slot = c & 7;
        int ss = slot ^ (row & 7);
        bg[i] = (const char*)w2b + ((size_t)e * HID + (n0 + row)) * (INTER * 2) + ss * 16;
    }

    f32x4 acc[4][4];
    #pragma unroll
    for (int m = 0; m < 4; m++)
        #pragma unroll
        for (int n = 0; n < 4; n++) acc[m][n] = (f32x4){0.f, 0.f, 0.f, 0.f};

    for (int k0 = 0; k0 < INTER; k0 += 64) {
        __syncthreads();
        #pragma unroll
        for (int i = 0; i < 2; i++)
            async16(ag[i] + k0 * 2, asl + (i * 512 + w * 64) * 16);
        #pragma unroll
        for (int i = 0; i < 4; i++)
            async16(bg[i] + k0 * 2, bsl + (i * 512 + w * 64) * 16);
        __syncthreads();
        #pragma unroll
        for (int kk = 0; kk < 2; kk++) {
            short8 af[4], bq[4];
            #pragma unroll
            for (int m = 0; m < 4; m++) {
                int row = wr * 64 + m * 16 + lo;
                int slot = (kk * 4 + hi) ^ (row & 7);
                af[m] = *(const short8*)(asl + row * 128 + slot * 16);
            }
            #pragma unroll
            for (int n = 0; n < 4; n++) {
                int brow = wc * 64 + n * 16 + lo;
                int slot = (kk * 4 + hi) ^ (brow & 7);
                bq[n] = *(const short8*)(bsl + brow * 128 + slot * 16);
            }
            #pragma unroll
            for (int m = 0; m < 4; m++)
                #pragma unroll
                for (int n = 0; n < 4; n++)
                    acc[m][n] = __builtin_amdgcn_mfma_f32_16x16x32_bf16(af[m], bq[n], acc[m][n], 0, 0, 0);
        }
    }

    __syncthreads();
    int* tb = (int*)As;
    float* wb = (float*)Bs;
    if (tid < 128) {
        int tr = moff + tid;
        bool v = tr < cnt;
        tb[tid] = v ? list_tok[base + tr] : -1;
        wb[tid] = v ? list_w[base + tr] : 0.f;
    }
    __syncthreads();

    #pragma unroll
    for (int m = 0; m < 4; m++) {
        int rbase = wr * 64 + m * 16 + hi * 4;
        #pragma unroll
        for (int r = 0; r < 4; r++) {
            int lrow = rbase + r;
            int tok = tb[lrow];
            if (tok < 0) continue;
            float ww = wb[lrow];
            float* orow = out + (size_t)tok * HID + n0 + wc * 64 + lo;
            #pragma unroll
            for (int n = 0; n < 4; n++)
                atomicAdd(orow + n * 16, ww * acc[m][n][r]);
        }
    }
}

// ---------- launch ----------
extern "C" void kernel_launch(void* const* d_in, const int* in_sizes, int n_in,
                              void* d_out, int out_size, void* d_ws, size_t ws_size,
                              hipStream_t stream) {
    const float* hs  = (const float*)d_in[0];
    const float* rl  = (const float*)d_in[1];
    const float* w13 = (const float*)d_in[2];
    const float* w2  = (const float*)d_in[3];
    float* out = (float*)d_out;
    char* ws = (char*)d_ws;

    short* hbf     = (short*)(ws + OFF_HBF);
    short* act     = (short*)(ws + OFF_ACT);
    int*   counts  = (int*)(ws + OFF_CNT);
    int*   cursors = (int*)(ws + OFF_CUR);
    int*   offsets = (int*)(ws + OFF_OFS);
    int*   topk_e  = (int*)(ws + OFF_TKE);
    float* topk_w  = (float*)(ws + OFF_TKW);
    int*   list_tok= (int*)(ws + OFF_LT);
    float* list_w  = (float*)(ws + OFF_LW);
    short* w13b    = (short*)(ws + OFF_W13B);
    short* w2b     = (short*)(ws + OFF_W2B);

    hipMemsetAsync(counts, 0, 64, stream);  // counts + cursors
    hipMemsetAsync(out, 0, (size_t)T_TOK * HID * sizeof(float), stream);

    k_route<<<T_TOK / 256, 256, 0, stream>>>(rl, counts, topk_e, topk_w);
    k_scan<<<1, 64, 0, stream>>>(counts, offsets);
    k_scatter<<<T_TOK / 256, 256, 0, stream>>>(topk_e, topk_w, offsets, cursors, list_tok, list_w);
    k_convert<<<(T_TOK * HID / 8) / 256, 256, 0, stream>>>(hs, hbf, T_TOK * HID / 8);

    const int n8_w13 = NEXP * 2 * INTER * HID / 8;   // 11,534,336
    const int n8_w2  = NEXP * HID * INTER / 8;       //  5,767,168
    k_convert<<<(n8_w13 + 255) / 256, 256, 0, stream>>>(w13, w13b, n8_w13);
    k_convert<<<(n8_w2 + 255) / 256, 256, 0, stream>>>(w2, w2b, n8_w2);

    k_gemm1_bf<<<dim3(INTER / 128, 32, NEXP), 512, 0, stream>>>(w13b, hbf, act, counts, offsets, list_tok);
    k_gemm2_bf<<<dim3(HID / 256, 32, NEXP), 512, 0, stream>>>(w2b, act, out, counts, offsets, list_tok, list_w);
}